// Round 17
// baseline (363.207 us; speedup 1.0000x reference)
//
#include <hip/hip_runtime.h>
#include <hip/hip_bf16.h>
#include <math.h>

#define EMBED 1024
#define FFN   4096
#define NW    8
#define MTOT  32768   // 16*2048

#define BM 256
#define BN 128
#define BK 64
#define NT (FFN / BK)   // 64 K-tiles

#define STRIP 128
#define KPT   8

typedef __attribute__((ext_vector_type(8))) short          short8v;
typedef __attribute__((ext_vector_type(8))) unsigned short ushort8v;
typedef __attribute__((ext_vector_type(4))) float          f32x4;

typedef __attribute__((address_space(1))) void gvoid_t;
typedef __attribute__((address_space(3))) void svoid_t;

static __device__ __forceinline__ unsigned short bf16bits(float f) {
    __hip_bfloat16 h = __float2bfloat16(f);
    return *reinterpret_cast<unsigned short*>(&h);
}

// ---------------- W2 f32 -> bf16 (once, into ws) ----------------
__global__ __launch_bounds__(256) void cvtW2_kernel(const float* __restrict__ W2,
                                                    __hip_bfloat16* __restrict__ Bw) {
    const long i0 = ((long)blockIdx.x * 256 + threadIdx.x) * 8;
    const float4 a = *(const float4*)(W2 + i0);
    const float4 b = *(const float4*)(W2 + i0 + 4);
    float fs[8] = {a.x, a.y, a.z, a.w, b.x, b.y, b.z, b.w};
    ushort8v v;
#pragma unroll
    for (int t = 0; t < 8; ++t) v[t] = bf16bits(fs[t]);
    *reinterpret_cast<ushort8v*>(Bw + i0) = v;
}

// ---------------- producer: h[m,k] = relu(b1[k] + qz[m,:]·W1[k,:]) ----------------
__global__ __launch_bounds__(256) void hprod2_kernel(
    const float* __restrict__ x, const float* __restrict__ theta,
    const float* __restrict__ W1, const float* __restrict__ b1,
    __hip_bfloat16* __restrict__ h, int m0)
{
    __shared__ float qz_lds[STRIP][NW];
    const int tid   = threadIdx.x;
    const int khalf = blockIdx.x & 1;
    const int strip = blockIdx.x >> 1;
    const int k0    = khalf * 2048 + tid * KPT;

    float w1r[KPT][NW];
    float b1r[KPT];
#pragma unroll
    for (int i = 0; i < KPT; ++i) {
        const float4 a = *(const float4*)(W1 + (long)(k0 + i) * NW);
        const float4 b = *(const float4*)(W1 + (long)(k0 + i) * NW + 4);
        w1r[i][0] = a.x; w1r[i][1] = a.y; w1r[i][2] = a.z; w1r[i][3] = a.w;
        w1r[i][4] = b.x; w1r[i][5] = b.y; w1r[i][6] = b.z; w1r[i][7] = b.w;
        b1r[i] = b1[k0 + i];
    }

    if (tid < STRIP) {
        const long m = (long)m0 + (long)strip * STRIP + tid;
        const float* xr = x + m * (long)EMBED;
#pragma unroll
        for (int w = 0; w < NW; ++w)
            qz_lds[tid][w] = cosf(xr[w]) * cosf(theta[w]);
    }
    __syncthreads();

    __hip_bfloat16* hp = h + ((long)strip * STRIP) * FFN + k0;
    for (int r = 0; r < STRIP; ++r) {
        float q[NW];
#pragma unroll
        for (int w = 0; w < NW; ++w) q[w] = qz_lds[r][w];
        ushort8v hv;
#pragma unroll
        for (int i = 0; i < KPT; ++i) {
            float acc = b1r[i];
#pragma unroll
            for (int w = 0; w < NW; ++w) acc = fmaf(q[w], w1r[i][w], acc);
            hv[i] = bf16bits(fmaxf(acc, 0.0f));
        }
        *reinterpret_cast<ushort8v*>(hp + (long)r * FFN) = hv;
    }
}

// ---------------- GEMM v17: R11 wave tile under the 256-reg ceiling ----------------
// out[M,1024] = h[M,4096] @ W2bf[1024,4096]^T + b2
// R16 arithmetic: LDS port ~80% busy at reads/MFMA=0.5 (64x64 wave tile) --
// the port is the wall, MFMA only 40%. The 128x64 wave tile (reads/MFMA =
// 0.375) is the one lever; R11 lost it to the register cliff (284 total regs
// -> 1 blk/CU). v17 engineers the budget:
//  * __launch_bounds__(256, 2): allocator targets <=256 total regs ->
//    8 waves/CU = 2 INDEPENDENT blocks (the m114 overlap mechanism).
//  * staging as #pragma unroll 1 loops w/ incremental pointers (R11's 12
//    unrolled DMA address pairs ~24 VGPR -> ~4).
//  * kk-major narrow liveness (bv[4] + single av), numerics identical to R11.
// LDS 48KB/block -> 2 blocks = 96KB. Zero-conflict swizzle pair + XCD map
// + plain __syncthreads structure unchanged (all R9/R12-proven).
__global__ __launch_bounds__(256, 2) void gemm17_kernel(
    const __hip_bfloat16* __restrict__ A,   // [rows][FFN] chunk-local h
    const __hip_bfloat16* __restrict__ Bw,  // [EMBED][FFN] W2 bf16
    const float* __restrict__ b2,
    float* __restrict__ out, long m0, int nPm)
{
    __shared__ __align__(16) __hip_bfloat16 As[BM * BK];  // 32 KB
    __shared__ __align__(16) __hip_bfloat16 Bs[BN * BK];  // 16 KB

    const int tid = threadIdx.x, wid = tid >> 6, lane = tid & 63;
    const int l15 = lane & 15, l4 = lane >> 4;
    const int wr = wid >> 1, wc = wid & 1;          // 2M x 2N wave grid

    // XCD map: bid = xcd + 8*j; per pm, 8 pn back-to-back on one XCD.
    const int xcd = blockIdx.x & 7, j = blockIdx.x >> 3;
    const int pn  = j & 7;
    const int pm  = xcd * (nPm >> 3) + (j >> 3);

    // staging: 8 threads/row (8x16B=128B row); sweeps of 32 rows.
    // Global source col pre-XORed by row&7 -> linear LDS + XOR'd read, 0 conf.
    const int srow  = tid >> 3;                     // 0..31
    const int colsw = ((tid & 7) ^ (srow & 7)) * 8;

    const __hip_bfloat16* AgT = A  + (long)(pm * BM + srow) * FFN + colsw;
    const __hip_bfloat16* BgT = Bw + (long)(pn * BN + srow) * FFN + colsw;

    f32x4 acc[8][4];
#pragma unroll
    for (int i = 0; i < 8; ++i)
#pragma unroll
        for (int jj = 0; jj < 4; ++jj) acc[i][jj] = (f32x4){0.f, 0.f, 0.f, 0.f};

    const int rx = (l15 & 7) << 3;   // read-side elem XOR; row&7 == l15&7

    for (int t = 0; t < NT; ++t) {
        __syncthreads();   // previous tile's reads complete before overwrite
        // staging with incremental pointers, NOT unrolled (register economy)
        {
            const __hip_bfloat16* pa = AgT;
            __hip_bfloat16* sa = &As[(wid * 8) * BK];
#pragma unroll 1
            for (int s = 0; s < 8; ++s) {
                __builtin_amdgcn_global_load_lds((gvoid_t*)pa, (svoid_t*)sa,
                                                 16, 0, 0);
                pa += (long)32 * FFN; sa += 32 * BK;
            }
            const __hip_bfloat16* pb = BgT;
            __hip_bfloat16* sb = &Bs[(wid * 8) * BK];
#pragma unroll 1
            for (int s = 0; s < 4; ++s) {
                __builtin_amdgcn_global_load_lds((gvoid_t*)pb, (svoid_t*)sb,
                                                 16, 0, 0);
                pb += (long)32 * FFN; sb += 32 * BK;
            }
        }
        AgT += BK; BgT += BK;
        __syncthreads();   // tile resident (vmcnt0 drain; sibling block hides)

        // kk-major: bv[4] read once per kk, reused by 8 mi; av single live
#pragma unroll
        for (int kk = 0; kk < 2; ++kk) {
            short8v bv[4];
#pragma unroll
            for (int ni = 0; ni < 4; ++ni) {
                const int row = wc * 64 + ni * 16 + l15;
                bv[ni] = *reinterpret_cast<const short8v*>(
                    &Bs[row * BK + ((kk * 32 + l4 * 8) ^ rx)]);
            }
#pragma unroll
            for (int mi = 0; mi < 8; ++mi) {
                const int row = wr * 128 + mi * 16 + l15;
                const short8v av = *reinterpret_cast<const short8v*>(
                    &As[row * BK + ((kk * 32 + l4 * 8) ^ rx)]);
#pragma unroll
                for (int ni = 0; ni < 4; ++ni)
                    acc[mi][ni] = __builtin_amdgcn_mfma_f32_16x16x32_bf16(
                        av, bv[ni], acc[mi][ni], 0, 0, 0);
            }
        }
    }

    // epilogue: + b2, f32 store. C/D: col=lane&15, row=(lane>>4)*4+reg
    const int gn0 = pn * BN + wc * 64;
    float bias[4];
#pragma unroll
    for (int ni = 0; ni < 4; ++ni) bias[ni] = b2[gn0 + ni * 16 + l15];
    const long gm0 = m0 + (long)pm * BM + wr * 128;
#pragma unroll
    for (int mi = 0; mi < 8; ++mi)
#pragma unroll
        for (int ni = 0; ni < 4; ++ni)
#pragma unroll
            for (int jj = 0; jj < 4; ++jj) {
                const long row = gm0 + mi * 16 + l4 * 4 + jj;
                out[row * EMBED + gn0 + ni * 16 + l15] = acc[mi][ni][jj] + bias[ni];
            }
}

extern "C" void kernel_launch(void* const* d_in, const int* in_sizes, int n_in,
                              void* d_out, int out_size, void* d_ws, size_t ws_size,
                              hipStream_t stream)
{
    const float* x     = (const float*)d_in[0];
    const float* theta = (const float*)d_in[1];
    const float* W1    = (const float*)d_in[2];
    const float* b1    = (const float*)d_in[3];
    const float* W2    = (const float*)d_in[4];
    const float* b2    = (const float*)d_in[5];
    float* out = (float*)d_out;

    const size_t w2b = (size_t)EMBED * FFN * 2;          // 8.4 MB bf16 W2
    __hip_bfloat16* Bw = (__hip_bfloat16*)d_ws;
    __hip_bfloat16* h  = (__hip_bfloat16*)((char*)d_ws + w2b);
    const size_t avail = ws_size > w2b ? ws_size - w2b : 0;

    long chunk = (long)((avail / ((size_t)FFN * 2)) & ~2047UL); // mult of 2048 rows
    if (chunk > MTOT) chunk = MTOT;
    if (chunk < 2048) chunk = 2048;

    cvtW2_kernel<<<(EMBED * FFN) / 2048, 256, 0, stream>>>(W2, Bw);

    for (long m0 = 0; m0 < MTOT; m0 += chunk) {
        const long rows = (MTOT - m0 < chunk) ? (MTOT - m0) : chunk;
        hprod2_kernel<<<(int)((rows / STRIP) * 2), 256, 0, stream>>>(
            x, theta, W1, b1, h, (int)m0);
        const int nPm = (int)(rows / BM);                 // multiple of 8
        gemm17_kernel<<<nPm * 8, 256, 0, stream>>>(h, Bw, b2, out, m0, nPm);
    }
}

// Round 18
// 358.635 us; speedup vs baseline: 1.0127x; 1.0127x over previous
//
#include <hip/hip_runtime.h>
#include <hip/hip_bf16.h>
#include <math.h>

#define EMBED 1024
#define FFN   4096
#define NW    8
#define MTOT  32768   // 16*2048

#define BM 128
#define BN 128
#define BK 64
#define NT (FFN / BK)   // 64 K-tiles

#define STRIP 128
#define KPT   8

typedef __attribute__((ext_vector_type(8))) short          short8v;
typedef __attribute__((ext_vector_type(8))) unsigned short ushort8v;
typedef __attribute__((ext_vector_type(4))) float          f32x4;

typedef __attribute__((address_space(1))) void gvoid_t;
typedef __attribute__((address_space(3))) void svoid_t;

static __device__ __forceinline__ unsigned short bf16bits(float f) {
    __hip_bfloat16 h = __float2bfloat16(f);
    return *reinterpret_cast<unsigned short*>(&h);
}

// ---------------- W2 f32 -> bf16 (once, into ws) ----------------
__global__ __launch_bounds__(256) void cvtW2_kernel(const float* __restrict__ W2,
                                                    __hip_bfloat16* __restrict__ Bw) {
    const long i0 = ((long)blockIdx.x * 256 + threadIdx.x) * 8;
    const float4 a = *(const float4*)(W2 + i0);
    const float4 b = *(const float4*)(W2 + i0 + 4);
    float fs[8] = {a.x, a.y, a.z, a.w, b.x, b.y, b.z, b.w};
    ushort8v v;
#pragma unroll
    for (int t = 0; t < 8; ++t) v[t] = bf16bits(fs[t]);
    *reinterpret_cast<ushort8v*>(Bw + i0) = v;
}

// ---------------- producer: h[m,k] = relu(b1[k] + qz[m,:]·W1[k,:]) ----------------
// W1 slice in registers, rows stream, qz broadcast from LDS. Write-BW-bound
// (~50us for 268MB = 5.4 TB/s, at the floor).
__global__ __launch_bounds__(256) void hprod2_kernel(
    const float* __restrict__ x, const float* __restrict__ theta,
    const float* __restrict__ W1, const float* __restrict__ b1,
    __hip_bfloat16* __restrict__ h, int m0)
{
    __shared__ float qz_lds[STRIP][NW];
    const int tid   = threadIdx.x;
    const int khalf = blockIdx.x & 1;
    const int strip = blockIdx.x >> 1;
    const int k0    = khalf * 2048 + tid * KPT;

    float w1r[KPT][NW];
    float b1r[KPT];
#pragma unroll
    for (int i = 0; i < KPT; ++i) {
        const float4 a = *(const float4*)(W1 + (long)(k0 + i) * NW);
        const float4 b = *(const float4*)(W1 + (long)(k0 + i) * NW + 4);
        w1r[i][0] = a.x; w1r[i][1] = a.y; w1r[i][2] = a.z; w1r[i][3] = a.w;
        w1r[i][4] = b.x; w1r[i][5] = b.y; w1r[i][6] = b.z; w1r[i][7] = b.w;
        b1r[i] = b1[k0 + i];
    }

    if (tid < STRIP) {
        const long m = (long)m0 + (long)strip * STRIP + tid;
        const float* xr = x + m * (long)EMBED;
#pragma unroll
        for (int w = 0; w < NW; ++w)
            qz_lds[tid][w] = cosf(xr[w]) * cosf(theta[w]);
    }
    __syncthreads();

    __hip_bfloat16* hp = h + ((long)strip * STRIP) * FFN + k0;
    for (int r = 0; r < STRIP; ++r) {
        float q[NW];
#pragma unroll
        for (int w = 0; w < NW; ++w) q[w] = qz_lds[r][w];
        ushort8v hv;
#pragma unroll
        for (int i = 0; i < KPT; ++i) {
            float acc = b1r[i];
#pragma unroll
            for (int w = 0; w < NW; ++w) acc = fmaf(q[w], w1r[i][w], acc);
            hv[i] = bf16bits(fmaxf(acc, 0.0f));
        }
        *reinterpret_cast<ushort8v*>(hp + (long)r * FFN) = hv;
    }
}

// ---------------- GEMM (R12 best structure + T5 setprio) ----------------
// out[M,1024] = h[M,4096] @ W2bf[1024,4096]^T + b2
// R12/R16 measured best (gemm ~304us, 898 TF). Each element evidence-backed:
//  * 128x128 tile, BK=64, 4 waves (2x2), 16x16x32 MFMA (2-way LDS alias =
//    free; 32x32 was 4-way = -18%, R13).
//  * kk-major narrow liveness: 56 VGPR + 64 AGPR = 120 < 128 cliff (m69)
//    -> ~3 independent blocks/CU; __launch_bounds__(256,4) pins it.
//  * plain __syncthreads loop: independent co-resident blocks overlap
//    read/MFMA/drain (m114); every explicit phase/vmcnt schedule measured
//    slower (R5-R8, R14, R15); big-tile port relief also slower (R11, R17).
//  * zero-conflict swizzle pair (src col ^ row&7 / read ^ row&7): 0 conflicts.
//  * XCD map: per pm, 8 pn consecutive on one XCD -> A panel L2-hot.
// NEW (R18): s_setprio(1) around the MFMA cluster. T5 mechanism matches
// THIS regime (multi-block, waves at different phases -> scheduler can
// prefer MFMA-issuing wave over sibling blocks' staging waves; m191 +4-7%).
// Null on lockstep schedules (m190) -- R12 is not lockstep across blocks.
__global__ __launch_bounds__(256, 4) void gemm18_kernel(
    const __hip_bfloat16* __restrict__ A,   // [rows][FFN] chunk-local h
    const __hip_bfloat16* __restrict__ Bw,  // [EMBED][FFN] W2 bf16
    const float* __restrict__ b2,
    float* __restrict__ out, long m0, int nPm)
{
    __shared__ __align__(16) __hip_bfloat16 As[BM * BK];  // 16 KB
    __shared__ __align__(16) __hip_bfloat16 Bs[BN * BK];  // 16 KB

    const int tid = threadIdx.x, wid = tid >> 6, lane = tid & 63;
    const int l15 = lane & 15, l4 = lane >> 4;
    const int wr = wid >> 1, wc = wid & 1;          // 2M x 2N wave grid

    // XCD map: bid = xcd + 8*j; per pm, 8 pn back-to-back on one XCD.
    const int xcd = blockIdx.x & 7, j = blockIdx.x >> 3;
    const int pn  = j & 7;
    const int pm  = xcd * (nPm >> 3) + (j >> 3);

    // staging: 8 threads/row (8x16B=128B row); 4 sweeps of 32 rows.
    const int srow  = tid >> 3;                     // 0..31
    const int colsw = ((tid & 7) ^ (srow & 7)) * 8;

    const __hip_bfloat16* Ag = A  + (long)(pm * BM + srow) * FFN + colsw;
    const __hip_bfloat16* Bg = Bw + (long)(pn * BN + srow) * FFN + colsw;

    f32x4 acc[4][4];
#pragma unroll
    for (int i = 0; i < 4; ++i)
#pragma unroll
        for (int jj = 0; jj < 4; ++jj) acc[i][jj] = (f32x4){0.f, 0.f, 0.f, 0.f};

    const int rx = (l15 & 7) << 3;   // read-side elem XOR; row&7 == l15&7

    for (int t = 0; t < NT; ++t) {
        __syncthreads();   // previous tile's reads complete before overwrite
#pragma unroll
        for (int s = 0; s < 4; ++s) {
            __builtin_amdgcn_global_load_lds(
                (gvoid_t*)(Ag + (long)(s * 32) * FFN + t * BK),
                (svoid_t*)(&As[(s * 32 + wid * 8) * BK]), 16, 0, 0);
            __builtin_amdgcn_global_load_lds(
                (gvoid_t*)(Bg + (long)(s * 32) * FFN + t * BK),
                (svoid_t*)(&Bs[(s * 32 + wid * 8) * BK]), 16, 0, 0);
        }
        __syncthreads();   // tile resident (vmcnt0 drain; sibling blocks hide)

        // kk-major: narrow liveness (bv[4]=16 + av=4 regs live, not 64)
#pragma unroll
        for (int kk = 0; kk < 2; ++kk) {
            short8v bv[4];
#pragma unroll
            for (int ni = 0; ni < 4; ++ni) {
                const int row = wc * 64 + ni * 16 + l15;
                bv[ni] = *reinterpret_cast<const short8v*>(
                    &Bs[row * BK + ((kk * 32 + l4 * 8) ^ rx)]);
            }
            __builtin_amdgcn_s_setprio(1);   // T5: favor MFMA wave vs sibling
#pragma unroll
            for (int mi = 0; mi < 4; ++mi) {
                const int row = wr * 64 + mi * 16 + l15;
                const short8v av = *reinterpret_cast<const short8v*>(
                    &As[row * BK + ((kk * 32 + l4 * 8) ^ rx)]);
#pragma unroll
                for (int ni = 0; ni < 4; ++ni)
                    acc[mi][ni] = __builtin_amdgcn_mfma_f32_16x16x32_bf16(
                        av, bv[ni], acc[mi][ni], 0, 0, 0);
            }
            __builtin_amdgcn_s_setprio(0);
        }
    }

    // epilogue: + b2, f32 store. C/D: col=lane&15, row=(lane>>4)*4+reg
    const int gn0 = pn * BN + wc * 64;
    float bias[4];
#pragma unroll
    for (int ni = 0; ni < 4; ++ni) bias[ni] = b2[gn0 + ni * 16 + l15];
    const long gm0 = m0 + (long)pm * BM + wr * 64;
#pragma unroll
    for (int mi = 0; mi < 4; ++mi)
#pragma unroll
        for (int ni = 0; ni < 4; ++ni)
#pragma unroll
            for (int jj = 0; jj < 4; ++jj) {
                const long row = gm0 + mi * 16 + l4 * 4 + jj;
                out[row * EMBED + gn0 + ni * 16 + l15] = acc[mi][ni][jj] + bias[ni];
            }
}

extern "C" void kernel_launch(void* const* d_in, const int* in_sizes, int n_in,
                              void* d_out, int out_size, void* d_ws, size_t ws_size,
                              hipStream_t stream)
{
    const float* x     = (const float*)d_in[0];
    const float* theta = (const float*)d_in[1];
    const float* W1    = (const float*)d_in[2];
    const float* b1    = (const float*)d_in[3];
    const float* W2    = (const float*)d_in[4];
    const float* b2    = (const float*)d_in[5];
    float* out = (float*)d_out;

    const size_t w2b = (size_t)EMBED * FFN * 2;          // 8.4 MB bf16 W2
    __hip_bfloat16* Bw = (__hip_bfloat16*)d_ws;
    __hip_bfloat16* h  = (__hip_bfloat16*)((char*)d_ws + w2b);
    const size_t avail = ws_size > w2b ? ws_size - w2b : 0;

    long chunk = (long)((avail / ((size_t)FFN * 2)) & ~2047UL); // mult of 2048 rows
    if (chunk > MTOT) chunk = MTOT;
    if (chunk < 2048) chunk = 2048;

    cvtW2_kernel<<<(EMBED * FFN) / 2048, 256, 0, stream>>>(W2, Bw);

    for (long m0 = 0; m0 < MTOT; m0 += chunk) {
        const long rows = (MTOT - m0 < chunk) ? (MTOT - m0) : chunk;
        hprod2_kernel<<<(int)((rows / STRIP) * 2), 256, 0, stream>>>(
            x, theta, W1, b1, h, (int)m0);
        const int nPm = (int)(rows / BM);                 // multiple of 16
        gemm18_kernel<<<nPm * 8, 256, 0, stream>>>(h, Bw, b2, out, m0, nPm);
    }
}